// Round 1
// baseline (354.993 us; speedup 1.0000x reference)
//
#include <hip/hip_runtime.h>

// Problem constants (B=1)
constexpr int L  = 2048;
constexpr int D  = 1024;
constexpr int H  = 16;
constexpr int F  = 16;   // qk feature dim per head
constexpr int HD = 64;   // v head dim
constexpr int CHUNK = 128;
constexpr int NC = L / CHUNK;  // 16

// ---------------------------------------------------------------------------
// fp32 GEMM: C[M,N] = A[M,K] @ B[K,N]; tiles BM=128 x BN=64, 256 threads,
// micro-tile 8x4 per thread. Requires M%128==0, N%64==0, K%16==0.
// ---------------------------------------------------------------------------
__global__ __launch_bounds__(256) void gemm_f32_128x64(
    const float* __restrict__ A, const float* __restrict__ B, float* __restrict__ C,
    int M, int N, int K) {
  constexpr int BM = 128, BN = 64, KT = 16;
  __shared__ float As[KT][BM + 4];  // transposed: As[k][m]; row=132 floats (16B aligned)
  __shared__ float Bs[KT][BN + 4];  // Bs[k][n]; row=68 floats (16B aligned)
  const int tid = threadIdx.x;
  const int tx = tid & 15;   // col group (x4)
  const int ty = tid >> 4;   // row group (x8)
  const int brow = blockIdx.y * BM;
  const int bcol = blockIdx.x * BN;
  float acc[8][4];
  #pragma unroll
  for (int r = 0; r < 8; ++r)
    #pragma unroll
    for (int c = 0; c < 4; ++c) acc[r][c] = 0.f;

  for (int k0 = 0; k0 < K; k0 += KT) {
    // stage A tile: 128 rows x 16 k  (512 float4, 2 per thread)
    #pragma unroll
    for (int i = 0; i < 2; ++i) {
      int g = i * 256 + tid;
      int m = g >> 2, kk = (g & 3) * 4;
      float4 av = *(const float4*)&A[(size_t)(brow + m) * K + (k0 + kk)];
      As[kk + 0][m] = av.x; As[kk + 1][m] = av.y;
      As[kk + 2][m] = av.z; As[kk + 3][m] = av.w;
    }
    // stage B tile: 16 k x 64 cols (256 float4, 1 per thread)
    {
      int kb = tid >> 4, nn = (tid & 15) * 4;
      *(float4*)&Bs[kb][nn] = *(const float4*)&B[(size_t)(k0 + kb) * N + (bcol + nn)];
    }
    __syncthreads();
    #pragma unroll
    for (int k = 0; k < KT; ++k) {
      float a[8], b[4];
      *(float4*)&a[0] = *(const float4*)&As[k][ty * 8];
      *(float4*)&a[4] = *(const float4*)&As[k][ty * 8 + 4];
      *(float4*)&b[0] = *(const float4*)&Bs[k][tx * 4];
      #pragma unroll
      for (int r = 0; r < 8; ++r)
        #pragma unroll
        for (int c = 0; c < 4; ++c)
          acc[r][c] = fmaf(a[r], b[c], acc[r][c]);
    }
    __syncthreads();
  }
  #pragma unroll
  for (int r = 0; r < 8; ++r)
    *(float4*)&C[(size_t)(brow + ty * 8 + r) * N + (bcol + tx * 4)] = *(float4*)&acc[r][0];
}

// ---------------------------------------------------------------------------
// Q/K projection with fp64 accumulation (den = q.cumsum(k) suffers catastrophic
// cancellation: fp32-accumulated q/k give ~3e-4 den error vs the ~3e-5 budget).
// C cols [0,256) -> Q via Wq ; [256,512) -> K via Wk. Stored as fp32.
// Tiles 64x64, 256 threads, micro 4x4. Grid (8, 32).
// ---------------------------------------------------------------------------
__global__ __launch_bounds__(256) void gemm_qk_f64(
    const float* __restrict__ hs, const float* __restrict__ Wq, const float* __restrict__ Wk,
    float* __restrict__ Qo, float* __restrict__ Ko) {
  constexpr int BT = 64, KT = 16, N = 256;
  __shared__ float As[KT][BT + 4];
  __shared__ float Bs[KT][BT + 4];
  const int tid = threadIdx.x;
  const int tx = tid & 15, ty = tid >> 4;
  const int colbase = blockIdx.x * BT;                 // 0..511
  const float* W = (colbase < 256) ? Wq : Wk;
  float* Out     = (colbase < 256) ? Qo : Ko;
  const int wcol = colbase & 255;
  const int brow = blockIdx.y * BT;
  double acc[4][4];
  #pragma unroll
  for (int r = 0; r < 4; ++r)
    #pragma unroll
    for (int c = 0; c < 4; ++c) acc[r][c] = 0.0;

  for (int k0 = 0; k0 < D; k0 += KT) {
    {
      int m = tid >> 2, kk = (tid & 3) * 4;
      float4 av = *(const float4*)&hs[(size_t)(brow + m) * D + (k0 + kk)];
      As[kk + 0][m] = av.x; As[kk + 1][m] = av.y;
      As[kk + 2][m] = av.z; As[kk + 3][m] = av.w;
    }
    {
      int kb = tid >> 4, nn = (tid & 15) * 4;
      *(float4*)&Bs[kb][nn] = *(const float4*)&W[(size_t)(k0 + kb) * N + (wcol + nn)];
    }
    __syncthreads();
    #pragma unroll
    for (int k = 0; k < KT; ++k) {
      float4 a4 = *(const float4*)&As[k][ty * 4];
      float4 b4 = *(const float4*)&Bs[k][tx * 4];
      double ad[4] = {(double)a4.x, (double)a4.y, (double)a4.z, (double)a4.w};
      double bd[4] = {(double)b4.x, (double)b4.y, (double)b4.z, (double)b4.w};
      #pragma unroll
      for (int r = 0; r < 4; ++r)
        #pragma unroll
        for (int c = 0; c < 4; ++c)
          acc[r][c] = fma(ad[r], bd[c], acc[r][c]);
    }
    __syncthreads();
  }
  #pragma unroll
  for (int r = 0; r < 4; ++r)
    #pragma unroll
    for (int c = 0; c < 4; ++c)
      Out[(size_t)(brow + ty * 4 + r) * N + (wcol + tx * 4 + c)] = (float)acc[r][c];
}

// ---------------------------------------------------------------------------
// Per-chunk state sums: Sc[h][c][f][e] = sum_{m in chunk c} k[m,h,f] * v[m,h,e]
// and ksum[h][c][f] = sum_m k[m,h,f] (fp64, feeds the denominator cumsum).
// Grid (NC, H), 256 threads.
// ---------------------------------------------------------------------------
__global__ __launch_bounds__(256) void chunk_state(
    const float* __restrict__ Kq, const float* __restrict__ V,
    float* __restrict__ Sc, double* __restrict__ ksum) {
  const int c = blockIdx.x, h = blockIdx.y;
  __shared__ float Ks[CHUNK][F];
  __shared__ float Vs[CHUNK][HD];
  const int tid = threadIdx.x;
  #pragma unroll
  for (int i = 0; i < 2; ++i) {
    int g = i * 256 + tid;
    int m = g >> 2, f0 = (g & 3) * 4;
    *(float4*)&Ks[m][f0] = *(const float4*)&Kq[(size_t)(c * CHUNK + m) * (H * F) + h * F + f0];
  }
  #pragma unroll
  for (int i = 0; i < 8; ++i) {
    int g = i * 256 + tid;
    int m = g >> 4, e0 = (g & 15) * 4;
    *(float4*)&Vs[m][e0] = *(const float4*)&V[(size_t)(c * CHUNK + m) * (H * HD) + h * HD + e0];
  }
  __syncthreads();
  const int f = tid >> 4, e0 = (tid & 15) * 4;
  float4 acc = make_float4(0.f, 0.f, 0.f, 0.f);
  for (int m = 0; m < CHUNK; ++m) {
    float kv = Ks[m][f];
    float4 v4 = *(const float4*)&Vs[m][e0];
    acc.x = fmaf(kv, v4.x, acc.x);
    acc.y = fmaf(kv, v4.y, acc.y);
    acc.z = fmaf(kv, v4.z, acc.z);
    acc.w = fmaf(kv, v4.w, acc.w);
  }
  *(float4*)&Sc[((((size_t)h * NC) + c) * F + f) * HD + e0] = acc;
  if (tid < F) {
    double s = 0.0;
    for (int m = 0; m < CHUNK; ++m) s += (double)Ks[m][tid];
    ksum[(((size_t)h * NC) + c) * F + tid] = s;
  }
}

// ---------------------------------------------------------------------------
// Exclusive prefix over chunks: Sin[h][c] = sum_{c'<c} Sc[h][c'] (fp32 state),
// kcum[h][c][f] = sum_{c'<c} ksum[h][c'][f] (fp64). Grid H, 1024 threads.
// ---------------------------------------------------------------------------
__global__ void prefix_state(const float* __restrict__ Sc, const double* __restrict__ ksum,
                             float* __restrict__ Sin, double* __restrict__ kcum) {
  const int h = blockIdx.x;
  const int tid = threadIdx.x;  // 0..1023 -> state element (f,e)
  float run = 0.f;
  for (int c = 0; c < NC; ++c) {
    size_t idx = (((size_t)h * NC) + c) * (F * HD) + tid;
    Sin[idx] = run;
    run += Sc[idx];
  }
  if (tid < F) {
    double rk = 0.0;
    for (int c = 0; c < NC; ++c) {
      size_t idx = (((size_t)h * NC) + c) * F + tid;
      kcum[idx] = rk;
      rk += ksum[idx];
    }
  }
}

// ---------------------------------------------------------------------------
// Fused chunk attention: per (chunk c, head h):
//   y_i = sum_{m<=i, in chunk} (q_i.k_m) v_m  +  q_i @ Sin   (fp32)
//   den_i = rowsum of masked q.k  +  q_i . kcum  (fp64 tail)
//   Ys[l, h*64+e] = y * 1/(den + 1e-12)
// 256 threads: thread = (row group of 4) x (col group of 8). Wave w only needs
// m < 32(w+1) for the intra part (causal early exit, wave-uniform).
// ---------------------------------------------------------------------------
__global__ __launch_bounds__(256) void attn_chunk(
    const float* __restrict__ Q, const float* __restrict__ Kq, const float* __restrict__ V,
    const float* __restrict__ Sin, const double* __restrict__ kcum,
    float* __restrict__ Ys) {
  const int c = blockIdx.x, h = blockIdx.y;
  __shared__ float Ks[CHUNK][F];
  __shared__ float Vs[CHUNK][HD];
  __shared__ float Ss[F][HD];
  __shared__ double kcs[F];
  __shared__ float zs[CHUNK];
  const int tid = threadIdx.x;

  #pragma unroll
  for (int i = 0; i < 2; ++i) {
    int g = i * 256 + tid;
    int m = g >> 2, f0 = (g & 3) * 4;
    *(float4*)&Ks[m][f0] = *(const float4*)&Kq[(size_t)(c * CHUNK + m) * (H * F) + h * F + f0];
  }
  #pragma unroll
  for (int i = 0; i < 8; ++i) {
    int g = i * 256 + tid;
    int m = g >> 4, e0 = (g & 15) * 4;
    *(float4*)&Vs[m][e0] = *(const float4*)&V[(size_t)(c * CHUNK + m) * (H * HD) + h * HD + e0];
  }
  {
    int f = tid >> 4, e0 = (tid & 15) * 4;
    *(float4*)&Ss[f][e0] = *(const float4*)&Sin[(((size_t)h * NC) + c) * (F * HD) + f * HD + e0];
  }
  if (tid < F) kcs[tid] = kcum[(((size_t)h * NC) + c) * F + tid];
  __syncthreads();

  const int rg = tid >> 3;      // 0..31
  const int cg = tid & 7;       // 0..7
  const int i0 = rg * 4;        // rows i0..i0+3
  const int e0 = cg * 8;        // cols e0..e0+7

  float q[4][F];
  #pragma unroll
  for (int r = 0; r < 4; ++r)
    #pragma unroll
    for (int f0 = 0; f0 < F; f0 += 4)
      *(float4*)&q[r][f0] = *(const float4*)&Q[(size_t)(c * CHUNK + i0 + r) * (H * F) + h * F + f0];

  float acc[4][8];
  #pragma unroll
  for (int r = 0; r < 4; ++r)
    #pragma unroll
    for (int j = 0; j < 8; ++j) acc[r][j] = 0.f;
  float den[4] = {0.f, 0.f, 0.f, 0.f};

  const int mmax = ((tid >> 6) + 1) * 32;   // wave-uniform causal bound
  for (int m = 0; m < mmax; ++m) {
    float kr[F];
    #pragma unroll
    for (int f0 = 0; f0 < F; f0 += 4)
      *(float4*)&kr[f0] = *(const float4*)&Ks[m][f0];
    float a[4];
    #pragma unroll
    for (int r = 0; r < 4; ++r) {
      float s = 0.f;
      #pragma unroll
      for (int f = 0; f < F; ++f) s = fmaf(q[r][f], kr[f], s);
      a[r] = (m <= i0 + r) ? s : 0.f;
      den[r] += a[r];
    }
    float v8[8];
    *(float4*)&v8[0] = *(const float4*)&Vs[m][e0];
    *(float4*)&v8[4] = *(const float4*)&Vs[m][e0 + 4];
    #pragma unroll
    for (int r = 0; r < 4; ++r)
      #pragma unroll
      for (int j = 0; j < 8; ++j)
        acc[r][j] = fmaf(a[r], v8[j], acc[r][j]);
  }

  // inter-chunk numerator: q @ Sin
  #pragma unroll
  for (int f = 0; f < F; ++f) {
    float s8[8];
    *(float4*)&s8[0] = *(const float4*)&Ss[f][e0];
    *(float4*)&s8[4] = *(const float4*)&Ss[f][e0 + 4];
    #pragma unroll
    for (int r = 0; r < 4; ++r)
      #pragma unroll
      for (int j = 0; j < 8; ++j)
        acc[r][j] = fmaf(q[r][f], s8[j], acc[r][j]);
  }

  if (cg == 0) {
    #pragma unroll
    for (int r = 0; r < 4; ++r) {
      double dd = (double)den[r];
      #pragma unroll
      for (int f = 0; f < F; ++f) dd += (double)q[r][f] * kcs[f];
      zs[i0 + r] = (float)(1.0 / (dd + 1e-12));
    }
  }
  __syncthreads();

  #pragma unroll
  for (int r = 0; r < 4; ++r) {
    float zz = zs[i0 + r];
    float o[8];
    #pragma unroll
    for (int j = 0; j < 8; ++j) o[j] = acc[r][j] * zz;
    size_t base = (size_t)(c * CHUNK + i0 + r) * (H * HD) + h * HD + e0;
    *(float4*)&Ys[base]     = *(float4*)&o[0];
    *(float4*)&Ys[base + 4] = *(float4*)&o[4];
  }
}

// ---------------------------------------------------------------------------
extern "C" void kernel_launch(void* const* d_in, const int* in_sizes, int n_in,
                              void* d_out, int out_size, void* d_ws, size_t ws_size,
                              hipStream_t stream) {
  const float* hs = (const float*)d_in[0];
  const float* Wq = (const float*)d_in[1];
  const float* Wk = (const float*)d_in[2];
  const float* Wv = (const float*)d_in[3];
  const float* Wo = (const float*)d_in[4];
  float* out = (float*)d_out;

  char* ws = (char*)d_ws;
  float*  Qb   = (float*)(ws + ((size_t)0  << 20));   // 2 MB  [L][H*F]
  float*  Kb   = (float*)(ws + ((size_t)2  << 20));   // 2 MB  [L][H*F]
  float*  Vb   = (float*)(ws + ((size_t)4  << 20));   // 8 MB  [L][H*HD]
  float*  Ys   = (float*)(ws + ((size_t)12 << 20));   // 8 MB  [L][H*HD]
  float*  Sc   = (float*)(ws + ((size_t)20 << 20));   // 1 MB  [H][NC][F][HD]
  float*  Sin  = (float*)(ws + ((size_t)21 << 20));   // 1 MB
  double* ksum = (double*)(ws + ((size_t)22 << 20));  // 32 KB [H][NC][F]
  double* kcum = (double*)(ws + ((size_t)22 << 20) + ((size_t)1 << 19));  // 32 KB

  // 1) Q,K projection (fp64 accumulate -> fp32 store)
  gemm_qk_f64<<<dim3(8, 32), 256, 0, stream>>>(hs, Wq, Wk, Qb, Kb);
  // 2) V projection (fp32)
  gemm_f32_128x64<<<dim3(1024 / 64, 2048 / 128), 256, 0, stream>>>(hs, Wv, Vb, L, H * HD, D);
  // 3) per-chunk k^T v states + fp64 k sums
  chunk_state<<<dim3(NC, H), 256, 0, stream>>>(Kb, Vb, Sc, ksum);
  // 4) exclusive prefix over chunks
  prefix_state<<<H, 1024, 0, stream>>>(Sc, ksum, Sin, kcum);
  // 5) fused chunk attention + denominator + scale
  attn_chunk<<<dim3(NC, H), 256, 0, stream>>>(Qb, Kb, Vb, Sin, kcum, Ys);
  // 6) output projection (fp32)
  gemm_f32_128x64<<<dim3(1024 / 64, 2048 / 128), 256, 0, stream>>>(Ys, Wo, out, L, D, H * HD);
}

// Round 2
// 210.610 us; speedup vs baseline: 1.6856x; 1.6856x over previous
//
#include <hip/hip_runtime.h>

// Problem constants (B=1)
constexpr int L  = 2048;
constexpr int D  = 1024;
constexpr int H  = 16;
constexpr int F  = 16;   // qk feature dim per head
constexpr int HD = 64;   // v head dim
constexpr int CHUNK = 128;
constexpr int NC = L / CHUNK;  // 16

typedef __bf16 bf16x8 __attribute__((ext_vector_type(8)));
typedef float  f32x16 __attribute__((ext_vector_type(16)));

__device__ __forceinline__ ushort f2bf(float f) {
  uint u = __builtin_bit_cast(uint, f);
  uint r = (u + 0x7FFFu + ((u >> 16) & 1u)) >> 16;
  return (ushort)r;
}
__device__ __forceinline__ float bf2f(ushort h) {
  uint u = ((uint)h) << 16;
  return __builtin_bit_cast(float, u);
}

// ---------------------------------------------------------------------------
// Row-preserving split: X (fp32) -> hi/lo bf16 (same layout). n elems, n%4==0.
// ---------------------------------------------------------------------------
__global__ __launch_bounds__(256) void split_rows(
    const float* __restrict__ X, ushort* __restrict__ hi, ushort* __restrict__ lo, int n4) {
  int idx = blockIdx.x * 256 + threadIdx.x;
  if (idx >= n4) return;
  float4 v = ((const float4*)X)[idx];
  ushort4 h, l;
  h.x = f2bf(v.x); l.x = f2bf(v.x - bf2f(h.x));
  h.y = f2bf(v.y); l.y = f2bf(v.y - bf2f(h.y));
  h.z = f2bf(v.z); l.z = f2bf(v.z - bf2f(h.z));
  h.w = f2bf(v.w); l.w = f2bf(v.w - bf2f(h.w));
  ((ushort4*)hi)[idx] = h;
  ((ushort4*)lo)[idx] = l;
}

// ---------------------------------------------------------------------------
// Split + transpose for 1024x1024 weights: W[k][n] fp32 -> WT_hi/lo[n][k] bf16.
// blockIdx.z selects (Wv -> WvT) or (Wo -> WoT). Grid (32,32,2), 256 thr.
// ---------------------------------------------------------------------------
__global__ __launch_bounds__(256) void wsplit_t(
    const float* __restrict__ W0, const float* __restrict__ W1,
    ushort* __restrict__ h0, ushort* __restrict__ l0,
    ushort* __restrict__ h1, ushort* __restrict__ l1) {
  const float* W = blockIdx.z ? W1 : W0;
  ushort* hiT = blockIdx.z ? h1 : h0;
  ushort* loT = blockIdx.z ? l1 : l0;
  __shared__ float t[32][33];
  const int tid = threadIdx.x;
  const int lx = tid & 31, ly = tid >> 5;          // ly 0..7
  const int bn = blockIdx.x * 32, bk = blockIdx.y * 32;
  #pragma unroll
  for (int i = 0; i < 32; i += 8)
    t[ly + i][lx] = W[(size_t)(bk + ly + i) * 1024 + bn + lx];  // t[k][n]
  __syncthreads();
  #pragma unroll
  for (int i = 0; i < 32; i += 8) {
    float v = t[lx][ly + i];                        // k=bk+lx, n=bn+ly+i
    ushort hh = f2bf(v);
    ushort ll = f2bf(v - bf2f(hh));
    hiT[(size_t)(bn + ly + i) * 1024 + bk + lx] = hh;
    loT[(size_t)(bn + ly + i) * 1024 + bk + lx] = ll;
  }
}

// ---------------------------------------------------------------------------
// bf16x2-split GEMM with MFMA: C[M,N] fp32 = Ah@B + Al@B  (B given transposed
// as BT[N][K], split into BTh/BTl). 3 product passes fused per K-step:
//   acc += Ah*Bh + Ah*Bl + Al*Bh      (Al*Bl dropped: ~2^-18 relative)
// Tile 64x64, BK=32, 256 threads = 4 waves; wave -> 32x32 quadrant via
// mfma_f32_32x32x16_bf16. LDS rows padded to 40 bf16 (80 B, 16B-aligned).
// ---------------------------------------------------------------------------
__global__ __launch_bounds__(256) void gemm_split_bf16(
    const ushort* __restrict__ Ah, const ushort* __restrict__ Al,
    const ushort* __restrict__ BTh, const ushort* __restrict__ BTl,
    float* __restrict__ C, int M, int N, int K) {
  constexpr int LDT = 40;
  __shared__ __bf16 As[2][64][LDT];
  __shared__ __bf16 Bs[2][64][LDT];
  const int tid  = threadIdx.x;
  const int wave = tid >> 6, lane = tid & 63;
  const int wr = (wave >> 1) * 32, wc = (wave & 1) * 32;
  const int brow = blockIdx.y * 64, bcol = blockIdx.x * 64;
  const int srow = tid >> 2, skg = (tid & 3) * 8;
  const size_t a_off = (size_t)(brow + srow) * K + skg;
  const size_t b_off = (size_t)(bcol + srow) * K + skg;

  f32x16 acc;
  #pragma unroll
  for (int i = 0; i < 16; ++i) acc[i] = 0.f;

  for (int k0 = 0; k0 < K; k0 += 32) {
    *(bf16x8*)&As[0][srow][skg] = *(const bf16x8*)&Ah[a_off + k0];
    *(bf16x8*)&As[1][srow][skg] = *(const bf16x8*)&Al[a_off + k0];
    *(bf16x8*)&Bs[0][srow][skg] = *(const bf16x8*)&BTh[b_off + k0];
    *(bf16x8*)&Bs[1][srow][skg] = *(const bf16x8*)&BTl[b_off + k0];
    __syncthreads();
    const int fr = lane & 31;
    const int kh = (lane >> 5) * 8;
    bf16x8 ah0 = *(const bf16x8*)&As[0][wr + fr][kh];
    bf16x8 ah1 = *(const bf16x8*)&As[0][wr + fr][16 + kh];
    bf16x8 al0 = *(const bf16x8*)&As[1][wr + fr][kh];
    bf16x8 al1 = *(const bf16x8*)&As[1][wr + fr][16 + kh];
    bf16x8 bh0 = *(const bf16x8*)&Bs[0][wc + fr][kh];
    bf16x8 bh1 = *(const bf16x8*)&Bs[0][wc + fr][16 + kh];
    bf16x8 bl0 = *(const bf16x8*)&Bs[1][wc + fr][kh];
    bf16x8 bl1 = *(const bf16x8*)&Bs[1][wc + fr][16 + kh];
    acc = __builtin_amdgcn_mfma_f32_32x32x16_bf16(ah0, bh0, acc, 0, 0, 0);
    acc = __builtin_amdgcn_mfma_f32_32x32x16_bf16(ah1, bh1, acc, 0, 0, 0);
    acc = __builtin_amdgcn_mfma_f32_32x32x16_bf16(ah0, bl0, acc, 0, 0, 0);
    acc = __builtin_amdgcn_mfma_f32_32x32x16_bf16(ah1, bl1, acc, 0, 0, 0);
    acc = __builtin_amdgcn_mfma_f32_32x32x16_bf16(al0, bh0, acc, 0, 0, 0);
    acc = __builtin_amdgcn_mfma_f32_32x32x16_bf16(al1, bh1, acc, 0, 0, 0);
    __syncthreads();
  }
  const int fr = lane & 31, fq = lane >> 5;
  #pragma unroll
  for (int r = 0; r < 16; ++r) {
    int row = brow + wr + (r & 3) + 8 * (r >> 2) + 4 * fq;
    C[(size_t)row * N + bcol + wc + fr] = acc[r];
  }
}

// ---------------------------------------------------------------------------
// Q/K projection, fp64 accumulation. v2: 32x64 tiles -> grid 512 (2 blocks/CU),
// fp32->fp64 conversion hoisted into LDS staging; inner loop pure v_fma_f64.
// C cols [0,256) -> Q via Wq ; [256,512) -> K via Wk. Micro-tile 2x4.
// ---------------------------------------------------------------------------
__global__ __launch_bounds__(256) void gemm_qk_f64_v2(
    const float* __restrict__ hs, const float* __restrict__ Wq, const float* __restrict__ Wk,
    float* __restrict__ Qo, float* __restrict__ Ko) {
  constexpr int LDA = 34, LDB = 68;  // f64 elems; rows 16B-aligned
  __shared__ double Asd[16][LDA];    // [k][m], 32 rows used
  __shared__ double Bsd[16][LDB];    // [k][n], 64 cols used
  const int tid = threadIdx.x;
  const int tx = tid & 15, ty = tid >> 4;
  const int brow = blockIdx.y * 32;
  const int colbase = blockIdx.x * 64;            // 0..511
  const float* W = (colbase < 256) ? Wq : Wk;
  float* Out     = (colbase < 256) ? Qo : Ko;
  const int wcol = colbase & 255;
  double acc[2][4] = {};

  for (int k0 = 0; k0 < D; k0 += 16) {
    if (tid < 128) {
      int m = tid >> 2, kk = (tid & 3) * 4;
      float4 av = *(const float4*)&hs[(size_t)(brow + m) * D + k0 + kk];
      Asd[kk + 0][m] = (double)av.x; Asd[kk + 1][m] = (double)av.y;
      Asd[kk + 2][m] = (double)av.z; Asd[kk + 3][m] = (double)av.w;
    }
    {
      int kb = tid >> 4, nn = (tid & 15) * 4;
      float4 bv = *(const float4*)&W[(size_t)(k0 + kb) * 256 + wcol + nn];
      Bsd[kb][nn + 0] = (double)bv.x; Bsd[kb][nn + 1] = (double)bv.y;
      Bsd[kb][nn + 2] = (double)bv.z; Bsd[kb][nn + 3] = (double)bv.w;
    }
    __syncthreads();
    #pragma unroll
    for (int k = 0; k < 16; ++k) {
      double a0 = Asd[k][ty * 2], a1 = Asd[k][ty * 2 + 1];
      double b0 = Bsd[k][tx * 4 + 0], b1 = Bsd[k][tx * 4 + 1];
      double b2 = Bsd[k][tx * 4 + 2], b3 = Bsd[k][tx * 4 + 3];
      acc[0][0] = fma(a0, b0, acc[0][0]); acc[0][1] = fma(a0, b1, acc[0][1]);
      acc[0][2] = fma(a0, b2, acc[0][2]); acc[0][3] = fma(a0, b3, acc[0][3]);
      acc[1][0] = fma(a1, b0, acc[1][0]); acc[1][1] = fma(a1, b1, acc[1][1]);
      acc[1][2] = fma(a1, b2, acc[1][2]); acc[1][3] = fma(a1, b3, acc[1][3]);
    }
    __syncthreads();
  }
  #pragma unroll
  for (int r = 0; r < 2; ++r)
    #pragma unroll
    for (int c = 0; c < 4; ++c)
      Out[(size_t)(brow + ty * 2 + r) * 256 + wcol + tx * 4 + c] = (float)acc[r][c];
}

// ---------------------------------------------------------------------------
// Per-chunk state sums: Sc[h][c][f][e] = sum_{m in chunk c} k[m,h,f] * v[m,h,e]
// and ksum[h][c][f] = sum_m k[m,h,f] (fp64). Grid (NC, H), 256 threads.
// ---------------------------------------------------------------------------
__global__ __launch_bounds__(256) void chunk_state(
    const float* __restrict__ Kq, const float* __restrict__ V,
    float* __restrict__ Sc, double* __restrict__ ksum) {
  const int c = blockIdx.x, h = blockIdx.y;
  __shared__ float Ks[CHUNK][F];
  __shared__ float Vs[CHUNK][HD];
  const int tid = threadIdx.x;
  #pragma unroll
  for (int i = 0; i < 2; ++i) {
    int g = i * 256 + tid;
    int m = g >> 2, f0 = (g & 3) * 4;
    *(float4*)&Ks[m][f0] = *(const float4*)&Kq[(size_t)(c * CHUNK + m) * (H * F) + h * F + f0];
  }
  #pragma unroll
  for (int i = 0; i < 8; ++i) {
    int g = i * 256 + tid;
    int m = g >> 4, e0 = (g & 15) * 4;
    *(float4*)&Vs[m][e0] = *(const float4*)&V[(size_t)(c * CHUNK + m) * (H * HD) + h * HD + e0];
  }
  __syncthreads();
  const int f = tid >> 4, e0 = (tid & 15) * 4;
  float4 acc = make_float4(0.f, 0.f, 0.f, 0.f);
  for (int m = 0; m < CHUNK; ++m) {
    float kv = Ks[m][f];
    float4 v4 = *(const float4*)&Vs[m][e0];
    acc.x = fmaf(kv, v4.x, acc.x);
    acc.y = fmaf(kv, v4.y, acc.y);
    acc.z = fmaf(kv, v4.z, acc.z);
    acc.w = fmaf(kv, v4.w, acc.w);
  }
  *(float4*)&Sc[((((size_t)h * NC) + c) * F + f) * HD + e0] = acc;
  if (tid < F) {
    double s = 0.0;
    for (int m = 0; m < CHUNK; ++m) s += (double)Ks[m][tid];
    ksum[(((size_t)h * NC) + c) * F + tid] = s;
  }
}

// ---------------------------------------------------------------------------
// Exclusive prefix over chunks. Grid H, 1024 threads.
// ---------------------------------------------------------------------------
__global__ void prefix_state(const float* __restrict__ Sc, const double* __restrict__ ksum,
                             float* __restrict__ Sin, double* __restrict__ kcum) {
  const int h = blockIdx.x;
  const int tid = threadIdx.x;
  float run = 0.f;
  for (int c = 0; c < NC; ++c) {
    size_t idx = (((size_t)h * NC) + c) * (F * HD) + tid;
    Sin[idx] = run;
    run += Sc[idx];
  }
  if (tid < F) {
    double rk = 0.0;
    for (int c = 0; c < NC; ++c) {
      size_t idx = (((size_t)h * NC) + c) * F + tid;
      kcum[idx] = rk;
      rk += ksum[idx];
    }
  }
}

// ---------------------------------------------------------------------------
// Fused chunk attention; writes Ys directly as bf16 hi/lo splits (A-side of
// the Wo GEMM). Grid (NC, H), 256 threads.
// ---------------------------------------------------------------------------
__global__ __launch_bounds__(256) void attn_chunk(
    const float* __restrict__ Q, const float* __restrict__ Kq, const float* __restrict__ V,
    const float* __restrict__ Sin, const double* __restrict__ kcum,
    ushort* __restrict__ Ysh, ushort* __restrict__ Ysl) {
  const int c = blockIdx.x, h = blockIdx.y;
  __shared__ float Ks[CHUNK][F];
  __shared__ float Vs[CHUNK][HD];
  __shared__ float Ss[F][HD];
  __shared__ double kcs[F];
  __shared__ float zs[CHUNK];
  const int tid = threadIdx.x;

  #pragma unroll
  for (int i = 0; i < 2; ++i) {
    int g = i * 256 + tid;
    int m = g >> 2, f0 = (g & 3) * 4;
    *(float4*)&Ks[m][f0] = *(const float4*)&Kq[(size_t)(c * CHUNK + m) * (H * F) + h * F + f0];
  }
  #pragma unroll
  for (int i = 0; i < 8; ++i) {
    int g = i * 256 + tid;
    int m = g >> 4, e0 = (g & 15) * 4;
    *(float4*)&Vs[m][e0] = *(const float4*)&V[(size_t)(c * CHUNK + m) * (H * HD) + h * HD + e0];
  }
  {
    int f = tid >> 4, e0 = (tid & 15) * 4;
    *(float4*)&Ss[f][e0] = *(const float4*)&Sin[(((size_t)h * NC) + c) * (F * HD) + f * HD + e0];
  }
  if (tid < F) kcs[tid] = kcum[(((size_t)h * NC) + c) * F + tid];
  __syncthreads();

  const int rg = tid >> 3;
  const int cg = tid & 7;
  const int i0 = rg * 4;
  const int e0 = cg * 8;

  float q[4][F];
  #pragma unroll
  for (int r = 0; r < 4; ++r)
    #pragma unroll
    for (int f0 = 0; f0 < F; f0 += 4)
      *(float4*)&q[r][f0] = *(const float4*)&Q[(size_t)(c * CHUNK + i0 + r) * (H * F) + h * F + f0];

  float acc[4][8];
  #pragma unroll
  for (int r = 0; r < 4; ++r)
    #pragma unroll
    for (int j = 0; j < 8; ++j) acc[r][j] = 0.f;
  float den[4] = {0.f, 0.f, 0.f, 0.f};

  const int mmax = ((tid >> 6) + 1) * 32;
  for (int m = 0; m < mmax; ++m) {
    float kr[F];
    #pragma unroll
    for (int f0 = 0; f0 < F; f0 += 4)
      *(float4*)&kr[f0] = *(const float4*)&Ks[m][f0];
    float a[4];
    #pragma unroll
    for (int r = 0; r < 4; ++r) {
      float s = 0.f;
      #pragma unroll
      for (int f = 0; f < F; ++f) s = fmaf(q[r][f], kr[f], s);
      a[r] = (m <= i0 + r) ? s : 0.f;
      den[r] += a[r];
    }
    float v8[8];
    *(float4*)&v8[0] = *(const float4*)&Vs[m][e0];
    *(float4*)&v8[4] = *(const float4*)&Vs[m][e0 + 4];
    #pragma unroll
    for (int r = 0; r < 4; ++r)
      #pragma unroll
      for (int j = 0; j < 8; ++j)
        acc[r][j] = fmaf(a[r], v8[j], acc[r][j]);
  }

  #pragma unroll
  for (int f = 0; f < F; ++f) {
    float s8[8];
    *(float4*)&s8[0] = *(const float4*)&Ss[f][e0];
    *(float4*)&s8[4] = *(const float4*)&Ss[f][e0 + 4];
    #pragma unroll
    for (int r = 0; r < 4; ++r)
      #pragma unroll
      for (int j = 0; j < 8; ++j)
        acc[r][j] = fmaf(q[r][f], s8[j], acc[r][j]);
  }

  if (cg == 0) {
    #pragma unroll
    for (int r = 0; r < 4; ++r) {
      double dd = (double)den[r];
      #pragma unroll
      for (int f = 0; f < F; ++f) dd += (double)q[r][f] * kcs[f];
      zs[i0 + r] = (float)(1.0 / (dd + 1e-12));
    }
  }
  __syncthreads();

  #pragma unroll
  for (int r = 0; r < 4; ++r) {
    float zz = zs[i0 + r];
    ushort4 h4a, h4b, l4a, l4b;
    float o;
    o = acc[r][0] * zz; h4a.x = f2bf(o); l4a.x = f2bf(o - bf2f(h4a.x));
    o = acc[r][1] * zz; h4a.y = f2bf(o); l4a.y = f2bf(o - bf2f(h4a.y));
    o = acc[r][2] * zz; h4a.z = f2bf(o); l4a.z = f2bf(o - bf2f(h4a.z));
    o = acc[r][3] * zz; h4a.w = f2bf(o); l4a.w = f2bf(o - bf2f(h4a.w));
    o = acc[r][4] * zz; h4b.x = f2bf(o); l4b.x = f2bf(o - bf2f(h4b.x));
    o = acc[r][5] * zz; h4b.y = f2bf(o); l4b.y = f2bf(o - bf2f(h4b.y));
    o = acc[r][6] * zz; h4b.z = f2bf(o); l4b.z = f2bf(o - bf2f(h4b.z));
    o = acc[r][7] * zz; h4b.w = f2bf(o); l4b.w = f2bf(o - bf2f(h4b.w));
    size_t base = (size_t)(c * CHUNK + i0 + r) * (H * HD) + h * HD + e0;
    *(ushort4*)&Ysh[base]     = h4a;
    *(ushort4*)&Ysh[base + 4] = h4b;
    *(ushort4*)&Ysl[base]     = l4a;
    *(ushort4*)&Ysl[base + 4] = l4b;
  }
}

// ---------------------------------------------------------------------------
extern "C" void kernel_launch(void* const* d_in, const int* in_sizes, int n_in,
                              void* d_out, int out_size, void* d_ws, size_t ws_size,
                              hipStream_t stream) {
  const float* hs = (const float*)d_in[0];
  const float* Wq = (const float*)d_in[1];
  const float* Wk = (const float*)d_in[2];
  const float* Wv = (const float*)d_in[3];
  const float* Wo = (const float*)d_in[4];
  float* out = (float*)d_out;

  char* ws = (char*)d_ws;
  const size_t MB = 1 << 20;
  float*  Qb    = (float*)(ws + 0 * MB);    // 2 MB  [L][256]
  float*  Kb    = (float*)(ws + 2 * MB);    // 2 MB
  float*  Vb    = (float*)(ws + 4 * MB);    // 8 MB  [L][1024]
  float*  Sc    = (float*)(ws + 12 * MB);   // 1 MB
  float*  Sin   = (float*)(ws + 13 * MB);   // 1 MB
  double* ksum  = (double*)(ws + 14 * MB);            // 32 KB
  double* kcum  = (double*)(ws + 14 * MB + 65536);    // 32 KB
  ushort* hs_hi = (ushort*)(ws + 15 * MB);  // 4 MB  [L][D] bf16
  ushort* hs_lo = (ushort*)(ws + 19 * MB);  // 4 MB
  ushort* Ys_hi = hs_hi;                    // overlay: hs splits dead after V GEMM
  ushort* Ys_lo = hs_lo;
  ushort* WvT_hi = (ushort*)(ws + 23 * MB); // 2 MB  [1024][1024] bf16 (transposed)
  ushort* WvT_lo = (ushort*)(ws + 25 * MB);
  ushort* WoT_hi = (ushort*)(ws + 27 * MB);
  ushort* WoT_lo = (ushort*)(ws + 29 * MB);

  // 1) split hs -> bf16 hi/lo (A-side of V GEMM)
  split_rows<<<dim3((L * D / 4 + 255) / 256), 256, 0, stream>>>(hs, hs_hi, hs_lo, L * D / 4);
  // 2) split+transpose Wv, Wo -> bf16 hi/lo [N][K]
  wsplit_t<<<dim3(32, 32, 2), 256, 0, stream>>>(Wv, Wo, WvT_hi, WvT_lo, WoT_hi, WoT_lo);
  // 3) Q,K projection (fp64 accumulate -> fp32 store)
  gemm_qk_f64_v2<<<dim3(8, 64), 256, 0, stream>>>(hs, Wq, Wk, Qb, Kb);
  // 4) V projection: bf16x2-split MFMA
  gemm_split_bf16<<<dim3(1024 / 64, 2048 / 64), 256, 0, stream>>>(
      hs_hi, hs_lo, WvT_hi, WvT_lo, Vb, L, 1024, D);
  // 5) per-chunk k^T v states + fp64 k sums
  chunk_state<<<dim3(NC, H), 256, 0, stream>>>(Kb, Vb, Sc, ksum);
  // 6) exclusive prefix over chunks
  prefix_state<<<H, 1024, 0, stream>>>(Sc, ksum, Sin, kcum);
  // 7) fused chunk attention -> Ys bf16 hi/lo (overlays hs splits)
  attn_chunk<<<dim3(NC, H), 256, 0, stream>>>(Qb, Kb, Vb, Sin, kcum, Ys_hi, Ys_lo);
  // 8) output projection: bf16x2-split MFMA
  gemm_split_bf16<<<dim3(1024 / 64, 2048 / 64), 256, 0, stream>>>(
      Ys_hi, Ys_lo, WoT_hi, WoT_lo, out, L, D, H * HD);
}